// Round 1
// baseline (727.321 us; speedup 1.0000x reference)
//
#include <hip/hip_runtime.h>
#include <math.h>

#define B_ 8
#define T_ 12
#define N_ 1024
#define D_ 64
#define E_ 64
#define M_ 16
#define BT_ (B_*T_)
#define ROWS_ (B_*T_*N_)
#define PAD 68   // LDS row pitch in floats: 272B rows -> 16B aligned, conflict-free float4

__device__ __forceinline__ float elu1(float x) {
    return x > 0.0f ? x + 1.0f : __expf(x);
}

// ---------- shared tile helpers (64x64 tiles, 256 threads) ----------

// lds[c][r] = src[r*stride + c]  (transposed stage; coalesced global read)
__device__ __forceinline__ void stageT(const float* __restrict__ src, int stride,
                                       float* __restrict__ lds, int tid) {
#pragma unroll
    for (int i = 0; i < 16; ++i) {
        int idx = tid + i * 256;
        int r = idx >> 6, c = idx & 63;
        lds[c * PAD + r] = src[r * stride + c];
    }
}

// lds[r][c] = src[r*stride + c]  (natural stage)
__device__ __forceinline__ void stageN(const float* __restrict__ src, int stride,
                                       float* __restrict__ lds, int tid) {
#pragma unroll
    for (int i = 0; i < 16; ++i) {
        int idx = tid + i * 256;
        int r = idx >> 6, c = idx & 63;
        lds[r * PAD + c] = src[r * stride + c];
    }
}

// acc[i][j] += sum_k AsT[k][ty*4+i] * Bs[k][tx*4+j]
__device__ __forceinline__ void mac64(const float* __restrict__ AsT, const float* __restrict__ Bs,
                                      float acc[4][4], int ty, int tx) {
#pragma unroll 8
    for (int k = 0; k < 64; ++k) {
        float4 a = *(const float4*)(AsT + k * PAD + ty * 4);
        float4 b = *(const float4*)(Bs + k * PAD + tx * 4);
        float av[4] = {a.x, a.y, a.z, a.w};
        float bv[4] = {b.x, b.y, b.z, b.w};
#pragma unroll
        for (int i = 0; i < 4; ++i)
#pragma unroll
            for (int j = 0; j < 4; ++j)
                acc[i][j] = fmaf(av[i], bv[j], acc[i][j]);
    }
}

// bias + LayerNorm over the 64-wide row (held by 16 consecutive lanes) + store
__device__ __forceinline__ void ln_store(float acc[4][4], const float* __restrict__ bias,
                                         const float* __restrict__ g, const float* __restrict__ bb,
                                         float* __restrict__ orow, int ty, int tx) {
    float gg[4], bbv[4], bi[4];
#pragma unroll
    for (int j = 0; j < 4; ++j) {
        int o = tx * 4 + j;
        gg[j] = g[o]; bbv[j] = bb[o]; bi[j] = bias[o];
    }
#pragma unroll
    for (int i = 0; i < 4; ++i) {
        float v[4];
#pragma unroll
        for (int j = 0; j < 4; ++j) v[j] = acc[i][j] + bi[j];
        float s = v[0] + v[1] + v[2] + v[3];
        s += __shfl_xor(s, 1, 64); s += __shfl_xor(s, 2, 64);
        s += __shfl_xor(s, 4, 64); s += __shfl_xor(s, 8, 64);
        float mu = s * (1.0f / 64.0f);
        float q = 0.f;
#pragma unroll
        for (int j = 0; j < 4; ++j) { float d = v[j] - mu; q += d * d; }
        q += __shfl_xor(q, 1, 64); q += __shfl_xor(q, 2, 64);
        q += __shfl_xor(q, 4, 64); q += __shfl_xor(q, 8, 64);
        float rstd = rsqrtf(q * (1.0f / 64.0f) + 1e-5f);
        float4 o;
        o.x = (v[0] - mu) * rstd * gg[0] + bbv[0];
        o.y = (v[1] - mu) * rstd * gg[1] + bbv[1];
        o.z = (v[2] - mu) * rstd * gg[2] + bbv[2];
        o.w = (v[3] - mu) * rstd * gg[3] + bbv[3];
        *(float4*)(orow + (size_t)(ty * 4 + i) * 64 + tx * 4) = o;
    }
}

// ---------- K0a: phi_K[M,E], V[M,D], KtV[E,D] ----------
__global__ void k_precompute(const float* __restrict__ PHI, const float* __restrict__ WK,
                             const float* __restrict__ WV, float* __restrict__ phiK,
                             float* __restrict__ Vm, float* __restrict__ KtV) {
    __shared__ float sPhiK[M_ * E_];
    __shared__ float sV[M_ * D_];
    int tid = threadIdx.x;
    for (int i = tid; i < M_ * E_; i += 256) {
        int m = i >> 6, e = i & 63;
        float kk = 0.f, vv = 0.f;
        for (int j = 0; j < E_; ++j) {
            float p = PHI[m * E_ + j];
            kk += p * WK[e * E_ + j];   // K[m][e] = sum_j PHI[m][j] WK[e][j]
            vv += p * WV[e * E_ + j];   // V[m][d] = sum_j PHI[m][j] WV[d][j] (e plays d)
        }
        float pk = elu1(kk);
        sPhiK[i] = pk; phiK[i] = pk;
        sV[i] = vv;    Vm[i] = vv;
    }
    __syncthreads();
    for (int i = tid; i < E_ * D_; i += 256) {
        int e = i >> 6, d = i & 63;
        float acc = 0.f;
        for (int m = 0; m < M_; ++m) acc += sPhiK[m * E_ + e] * sV[m * D_ + d];
        KtV[i] = acc;   // KtV[e][d]
    }
}

// ---------- K0b: dinv[n] = rsqrt(sum_m A_static[n,m] + 1e-12) ----------
__global__ void k_dinv(const float* __restrict__ A, float* __restrict__ dinv) {
    int row = blockIdx.x;
    int tid = threadIdx.x;
    float s = 0.f;
    for (int i = tid; i < N_; i += 256) s += A[(size_t)row * N_ + i];
    for (int off = 32; off; off >>= 1) s += __shfl_xor(s, off, 64);
    __shared__ float red[4];
    if ((tid & 63) == 0) red[tid >> 6] = s;
    __syncthreads();
    if (tid == 0) dinv[row] = rsqrtf(red[0] + red[1] + red[2] + red[3] + 1e-12f);
}

// ---------- K1: phiQ = elu(H @ WQ^T) + 1, into BUF0 ----------
__global__ void k_phiq(const float* __restrict__ H, const float* __restrict__ WQ,
                       float* __restrict__ out) {
    __shared__ __align__(16) float AsT[64 * PAD];
    __shared__ __align__(16) float Bs[64 * PAD];
    int tid = threadIdx.x;
    const float* Arow = H + (size_t)blockIdx.x * 4096;
    stageT(Arow, 64, AsT, tid);
    stageT(WQ, 64, Bs, tid);           // Bs[d][e] = WQ[e][d]
    __syncthreads();
    int ty = tid >> 4, tx = tid & 15;
    float acc[4][4] = {};
    mac64(AsT, Bs, acc, ty, tx);
    float* orow = out + (size_t)blockIdx.x * 4096;
#pragma unroll
    for (int i = 0; i < 4; ++i) {
        float4 o;
        o.x = elu1(acc[i][0]); o.y = elu1(acc[i][1]);
        o.z = elu1(acc[i][2]); o.w = elu1(acc[i][3]);
        *(float4*)(orow + (size_t)(ty * 4 + i) * 64 + tx * 4) = o;
    }
}

// ---------- K2a: QK softmax over memory slots, mem_val, mean over t -> mv ----------
__global__ void k_attn_mem(const float* __restrict__ phiQ, const float* __restrict__ phiK,
                           const float* __restrict__ Vm, float* __restrict__ mv) {
    __shared__ float pkT[E_ * 17];        // pkT[e*17+m] = phiK[m][e]
    __shared__ float sV[M_ * D_];         // natural [m][d]
    __shared__ float pq[4][D_];           // per-wave phiQ row
    __shared__ float sa[4][M_];           // per-wave softmax weights
    int tid = threadIdx.x;
    for (int i = tid; i < M_ * E_; i += 256) {
        int m = i >> 6, e = i & 63;
        pkT[e * 17 + m] = phiK[m * E_ + e];
    }
    for (int i = tid; i < M_ * D_; i += 256) sV[i] = Vm[i];
    __syncthreads();
    int w = tid >> 6, lane = tid & 63;
    int b = blockIdx.x >> 8;              // 256 groups of 4 n per b
    int n = (blockIdx.x & 255) * 4 + w;
    int m = lane & 15, c = lane >> 4;
    float mvacc = 0.f;
    for (int t = 0; t < T_; ++t) {
        size_t rowoff = ((size_t)(b * T_ + t) * N_ + n) * 64;
        pq[w][lane] = phiQ[rowoff + lane];
        __syncthreads();
        float s = 0.f;
#pragma unroll
        for (int i = 0; i < 16; ++i) {
            int e = c * 16 + i;
            s += pq[w][e] * pkT[e * 17 + m];
        }
        s += __shfl_xor(s, 16, 64);
        s += __shfl_xor(s, 32, 64);
        s *= 0.125f;                       // / sqrt(E)
        float mx = s;
        mx = fmaxf(mx, __shfl_xor(mx, 1, 64)); mx = fmaxf(mx, __shfl_xor(mx, 2, 64));
        mx = fmaxf(mx, __shfl_xor(mx, 4, 64)); mx = fmaxf(mx, __shfl_xor(mx, 8, 64));
        float ex = __expf(s - mx);
        float sum = ex;
        sum += __shfl_xor(sum, 1, 64); sum += __shfl_xor(sum, 2, 64);
        sum += __shfl_xor(sum, 4, 64); sum += __shfl_xor(sum, 8, 64);
        float a = ex / sum;
        if (lane < 16) sa[w][lane] = a;
        __syncthreads();
        float mval = 0.f;
#pragma unroll
        for (int mm = 0; mm < 16; ++mm) mval += sa[w][mm] * sV[mm * D_ + lane];
        mvacc += mval;
        __syncthreads();
    }
    mv[((size_t)b * N_ + n) * 64 + lane] = mvacc * (1.0f / 12.0f);
}

// ---------- K2b: BUF0 = phiQ @ KtV + H_temp (in place) ----------
__global__ void k_matt(float* __restrict__ buf, const float* __restrict__ KtV,
                       const float* __restrict__ H) {
    __shared__ __align__(16) float AsT[64 * PAD];
    __shared__ __align__(16) float Bs[64 * PAD];
    int tid = threadIdx.x;
    float* rows = buf + (size_t)blockIdx.x * 4096;
    stageT(rows, 64, AsT, tid);
    stageN(KtV, 64, Bs, tid);          // Bs[e][d] = KtV[e][d]
    __syncthreads();
    int ty = tid >> 4, tx = tid & 15;
    float acc[4][4] = {};
    mac64(AsT, Bs, acc, ty, tx);
    const float* hrow = H + (size_t)blockIdx.x * 4096;
#pragma unroll
    for (int i = 0; i < 4; ++i) {
        float4 h = *(const float4*)(hrow + (size_t)(ty * 4 + i) * 64 + tx * 4);
        float4 o;
        o.x = acc[i][0] + h.x; o.y = acc[i][1] + h.y;
        o.z = acc[i][2] + h.z; o.w = acc[i][3] + h.w;
        *(float4*)(rows + (size_t)(ty * 4 + i) * 64 + tx * 4) = o;
    }
}

// ---------- K3: BUF0 = LN(BUF0 @ outW^T + outb; sma_g, sma_b) (in place) ----------
__global__ void k_outln(float* __restrict__ buf, const float* __restrict__ outW,
                        const float* __restrict__ outb, const float* __restrict__ g,
                        const float* __restrict__ bb) {
    __shared__ __align__(16) float AsT[64 * PAD];
    __shared__ __align__(16) float Bs[64 * PAD];
    int tid = threadIdx.x;
    float* rows = buf + (size_t)blockIdx.x * 4096;
    stageT(rows, 64, AsT, tid);
    stageT(outW, 64, Bs, tid);         // Bs[d][o] = outW[o][d]
    __syncthreads();
    int ty = tid >> 4, tx = tid & 15;
    float acc[4][4] = {};
    mac64(AsT, Bs, acc, ty, tx);
    ln_store(acc, outb, g, bb, rows, ty, tx);
}

// ---------- K4: A_dynamic + A_fused ----------
__global__ void k_adyn(const float* __restrict__ mv, const float* __restrict__ Ast,
                       const float* __restrict__ dinv, const float* __restrict__ beta,
                       float* __restrict__ Adyn, float* __restrict__ Afu) {
    __shared__ __align__(16) float mvn[8][PAD];
    __shared__ __align__(16) float tile[64][PAD];
    int tid = threadIdx.x;
    int b = blockIdx.x >> 7, n0 = (blockIdx.x & 127) * 8;
    const float* mvb = mv + (size_t)b * N_ * 64;
    for (int i = tid; i < 512; i += 256) {
        int r = i >> 6, d = i & 63;
        mvn[r][d] = mvb[(size_t)(n0 + r) * 64 + d];
    }
    __syncthreads();
    int nl = tid >> 5;        // 0..7
    int mi = tid & 31;        // 0..31
    float s[32];
    for (int mt = 0; mt < 16; ++mt) {
        if (mt) __syncthreads();
        for (int i = tid; i < 4096; i += 256) {
            int r = i >> 6, d = i & 63;
            tile[r][d] = mvb[(size_t)(mt * 64 + r) * 64 + d];
        }
        __syncthreads();
#pragma unroll
        for (int j = 0; j < 2; ++j) {
            int ml = mi + 32 * j;
            float dot = 0.f;
#pragma unroll
            for (int k4 = 0; k4 < 16; ++k4) {
                float4 x = *(const float4*)&mvn[nl][k4 * 4];
                float4 y = *(const float4*)&tile[ml][k4 * 4];
                dot += x.x * y.x + x.y * y.y + x.z * y.z + x.w * y.w;
            }
            s[mt * 2 + j] = dot * 0.125f;   // / sqrt(D)
        }
    }
    float mx = -3.4e38f;
#pragma unroll
    for (int i = 0; i < 32; ++i) mx = fmaxf(mx, s[i]);
    mx = fmaxf(mx, __shfl_xor(mx, 1, 64));  mx = fmaxf(mx, __shfl_xor(mx, 2, 64));
    mx = fmaxf(mx, __shfl_xor(mx, 4, 64));  mx = fmaxf(mx, __shfl_xor(mx, 8, 64));
    mx = fmaxf(mx, __shfl_xor(mx, 16, 64));
    float sum = 0.f;
#pragma unroll
    for (int i = 0; i < 32; ++i) { s[i] = __expf(s[i] - mx); sum += s[i]; }
    sum += __shfl_xor(sum, 1, 64);  sum += __shfl_xor(sum, 2, 64);
    sum += __shfl_xor(sum, 4, 64);  sum += __shfl_xor(sum, 8, 64);
    sum += __shfl_xor(sum, 16, 64);
    float inv = 1.0f / sum;
    float bta = fminf(fmaxf(beta[0], 0.0f), 1.0f);
    int n = n0 + nl;
    float dn = dinv[n];
    size_t rowo = ((size_t)b * N_ + n) * N_;
#pragma unroll
    for (int i = 0; i < 32; ++i) {
        int m = (i >> 1) * 64 + (i & 1) * 32 + mi;
        float ad = s[i] * inv;
        Adyn[rowo + m] = ad;
        Afu[rowo + m] = bta * ad + (1.0f - bta) * dn * Ast[(size_t)n * N_ + m] * dinv[m];
    }
}

// ---------- K5/K6: diffusion hop  Xout[bt] = A_fused[b] @ Xin[bt] ----------
__global__ void k_diffuse(const float* __restrict__ Afu, const float* __restrict__ Xin,
                          float* __restrict__ Xout) {
    __shared__ __align__(16) float AsT[64 * PAD];
    __shared__ __align__(16) float Bs[64 * PAD];
    int bt = blockIdx.y;
    int b = bt / T_;
    const float* A = Afu + (size_t)b * N_ * N_;
    const float* X = Xin + (size_t)bt * N_ * 64;
    float* O = Xout + (size_t)bt * N_ * 64;
    int n0 = blockIdx.x * 64;
    int tid = threadIdx.x, ty = tid >> 4, tx = tid & 15;
    float acc[4][4] = {};
    for (int mt = 0; mt < 16; ++mt) {
        if (mt) __syncthreads();
        stageT(A + (size_t)n0 * N_ + mt * 64, N_, AsT, tid);  // AsT[m][n]
        stageN(X + (size_t)mt * 64 * 64, 64, Bs, tid);        // Bs[m][d]
        __syncthreads();
        mac64(AsT, Bs, acc, ty, tx);
    }
#pragma unroll
    for (int i = 0; i < 4; ++i) {
        float4 o;
        o.x = acc[i][0]; o.y = acc[i][1]; o.z = acc[i][2]; o.w = acc[i][3];
        *(float4*)(O + (size_t)(n0 + ty * 4 + i) * 64 + tx * 4) = o;
    }
}

// ---------- K7: H_spatial = LN(cat(X0,X1,X2) @ projW^T + proj_b; agg) ----------
__global__ void k_projln(const float* __restrict__ X0, const float* __restrict__ X1,
                         const float* __restrict__ X2, const float* __restrict__ PW,
                         const float* __restrict__ pb, const float* __restrict__ g,
                         const float* __restrict__ bb, float* __restrict__ out) {
    __shared__ __align__(16) float AsT[64 * PAD];
    __shared__ __align__(16) float Bs[64 * PAD];
    int tid = threadIdx.x, ty = tid >> 4, tx = tid & 15;
    float acc[4][4] = {};
    const float* Xs[3] = {X0, X1, X2};
    for (int c = 0; c < 3; ++c) {
        if (c) __syncthreads();
        stageT(Xs[c] + (size_t)blockIdx.x * 4096, 64, AsT, tid);
        stageT(PW + c * 64, 192, Bs, tid);   // Bs[k][o] = PW[o][c*64+k]
        __syncthreads();
        mac64(AsT, Bs, acc, ty, tx);
    }
    ln_store(acc, pb, g, bb, out + (size_t)blockIdx.x * 4096, ty, tx);
}

// ---------- launch ----------
extern "C" void kernel_launch(void* const* d_in, const int* in_sizes, int n_in,
                              void* d_out, int out_size, void* d_ws, size_t ws_size,
                              hipStream_t stream) {
    const float* H    = (const float*)d_in[0];
    const float* Ast  = (const float*)d_in[1];
    const float* WQ   = (const float*)d_in[2];
    const float* WK   = (const float*)d_in[3];
    const float* WV   = (const float*)d_in[4];
    const float* PHI  = (const float*)d_in[5];
    const float* outW = (const float*)d_in[6];
    const float* outb = (const float*)d_in[7];
    const float* smag = (const float*)d_in[8];
    const float* smab = (const float*)d_in[9];
    const float* beta = (const float*)d_in[10];
    const float* PW   = (const float*)d_in[11];
    const float* pb   = (const float*)d_in[12];
    const float* aggg = (const float*)d_in[13];
    const float* aggb = (const float*)d_in[14];

    float* out  = (float*)d_out;
    float* Hsp  = out;                                   // [B,T,N,D]
    float* Adyn = out + (size_t)ROWS_ * 64;              // [B,N,N]
    float* Afu  = Adyn + (size_t)B_ * N_ * N_;           // [B,N,N]

    float* ws   = (float*)d_ws;
    float* BUF0 = ws;                                    // phiQ -> Hp -> H_prime (in place)
    float* X1   = BUF0 + (size_t)ROWS_ * 64;
    float* X2   = X1 + (size_t)ROWS_ * 64;
    float* mv   = X2 + (size_t)ROWS_ * 64;
    float* phiK = mv + (size_t)B_ * N_ * 64;
    float* Vm   = phiK + M_ * E_;
    float* KtV  = Vm + M_ * D_;
    float* dinv = KtV + E_ * D_;

    k_precompute<<<1, 256, 0, stream>>>(PHI, WK, WV, phiK, Vm, KtV);
    k_dinv<<<N_, 256, 0, stream>>>(Ast, dinv);
    k_phiq<<<ROWS_ / 64, 256, 0, stream>>>(H, WQ, BUF0);
    k_attn_mem<<<B_ * N_ / 4, 256, 0, stream>>>(BUF0, phiK, Vm, mv);
    k_matt<<<ROWS_ / 64, 256, 0, stream>>>(BUF0, KtV, H);
    k_outln<<<ROWS_ / 64, 256, 0, stream>>>(BUF0, outW, outb, smag, smab);
    k_adyn<<<B_ * N_ / 8, 256, 0, stream>>>(mv, Ast, dinv, beta, Adyn, Afu);
    k_diffuse<<<dim3(16, BT_), 256, 0, stream>>>(Afu, BUF0, X1);
    k_diffuse<<<dim3(16, BT_), 256, 0, stream>>>(Afu, X1, X2);
    k_projln<<<ROWS_ / 64, 256, 0, stream>>>(BUF0, X1, X2, PW, pb, aggg, aggb, Hsp);
}

// Round 2
// 393.326 us; speedup vs baseline: 1.8492x; 1.8492x over previous
//
#include <hip/hip_runtime.h>
#include <math.h>

#define B_ 8
#define T_ 12
#define N_ 1024
#define D_ 64
#define E_ 64
#define M_ 16
#define BT_ (B_*T_)
#define ROWS_ (B_*T_*N_)
#define PAD 68    // fp32 LDS pitch (272 B)
#define DPAD 72   // bf16 LDS pitch (144 B): 16B-aligned rows, +4-bank rotation/row

typedef __attribute__((ext_vector_type(8))) __bf16 bf16x8;
typedef __attribute__((ext_vector_type(4))) __bf16 bf16x4;
typedef __attribute__((ext_vector_type(4))) float f32x4;

__device__ __forceinline__ float elu1(float x) {
    return x > 0.0f ? x + 1.0f : __expf(x);
}

// ---------- fp32 tile helpers (64x64 tiles, 256 threads) ----------

__device__ __forceinline__ void stageT(const float* __restrict__ src, int stride,
                                       float* __restrict__ lds, int tid) {
#pragma unroll
    for (int i = 0; i < 16; ++i) {
        int idx = tid + i * 256;
        int r = idx >> 6, c = idx & 63;
        lds[c * PAD + r] = src[r * stride + c];
    }
}

__device__ __forceinline__ void stageN(const float* __restrict__ src, int stride,
                                       float* __restrict__ lds, int tid) {
#pragma unroll
    for (int i = 0; i < 16; ++i) {
        int idx = tid + i * 256;
        int r = idx >> 6, c = idx & 63;
        lds[r * PAD + c] = src[r * stride + c];
    }
}

__device__ __forceinline__ void mac64(const float* __restrict__ AsT, const float* __restrict__ Bs,
                                      float acc[4][4], int ty, int tx) {
#pragma unroll 8
    for (int k = 0; k < 64; ++k) {
        float4 a = *(const float4*)(AsT + k * PAD + ty * 4);
        float4 b = *(const float4*)(Bs + k * PAD + tx * 4);
        float av[4] = {a.x, a.y, a.z, a.w};
        float bv[4] = {b.x, b.y, b.z, b.w};
#pragma unroll
        for (int i = 0; i < 4; ++i)
#pragma unroll
            for (int j = 0; j < 4; ++j)
                acc[i][j] = fmaf(av[i], bv[j], acc[i][j]);
    }
}

// ---------- K0a ----------
__global__ void k_precompute(const float* __restrict__ PHI, const float* __restrict__ WK,
                             const float* __restrict__ WV, float* __restrict__ phiK,
                             float* __restrict__ Vm, float* __restrict__ KtV) {
    __shared__ float sPhiK[M_ * E_];
    __shared__ float sV[M_ * D_];
    int tid = threadIdx.x;
    for (int i = tid; i < M_ * E_; i += 256) {
        int m = i >> 6, e = i & 63;
        float kk = 0.f, vv = 0.f;
        for (int j = 0; j < E_; ++j) {
            float p = PHI[m * E_ + j];
            kk += p * WK[e * E_ + j];
            vv += p * WV[e * E_ + j];
        }
        float pk = elu1(kk);
        sPhiK[i] = pk; phiK[i] = pk;
        sV[i] = vv;    Vm[i] = vv;
    }
    __syncthreads();
    for (int i = tid; i < E_ * D_; i += 256) {
        int e = i >> 6, d = i & 63;
        float acc = 0.f;
        for (int m = 0; m < M_; ++m) acc += sPhiK[m * E_ + e] * sV[m * D_ + d];
        KtV[i] = acc;
    }
}

// ---------- K0b ----------
__global__ void k_dinv(const float* __restrict__ A, float* __restrict__ dinv) {
    int row = blockIdx.x;
    int tid = threadIdx.x;
    float s = 0.f;
    for (int i = tid; i < N_; i += 256) s += A[(size_t)row * N_ + i];
    for (int off = 32; off; off >>= 1) s += __shfl_xor(s, off, 64);
    __shared__ float red[4];
    if ((tid & 63) == 0) red[tid >> 6] = s;
    __syncthreads();
    if (tid == 0) dinv[row] = rsqrtf(red[0] + red[1] + red[2] + red[3] + 1e-12f);
}

// ---------- K1: phiQ ----------
__global__ void k_phiq(const float* __restrict__ H, const float* __restrict__ WQ,
                       float* __restrict__ out) {
    __shared__ __align__(16) float AsT[64 * PAD];
    __shared__ __align__(16) float Bs[64 * PAD];
    int tid = threadIdx.x;
    const float* Arow = H + (size_t)blockIdx.x * 4096;
    stageT(Arow, 64, AsT, tid);
    stageT(WQ, 64, Bs, tid);
    __syncthreads();
    int ty = tid >> 4, tx = tid & 15;
    float acc[4][4] = {};
    mac64(AsT, Bs, acc, ty, tx);
    float* orow = out + (size_t)blockIdx.x * 4096;
#pragma unroll
    for (int i = 0; i < 4; ++i) {
        float4 o;
        o.x = elu1(acc[i][0]); o.y = elu1(acc[i][1]);
        o.z = elu1(acc[i][2]); o.w = elu1(acc[i][3]);
        *(float4*)(orow + (size_t)(ty * 4 + i) * 64 + tx * 4) = o;
    }
}

// ---------- K2a: memory-slot softmax, mem_val, t-mean -> mv ----------
__global__ void k_attn_mem(const float* __restrict__ phiQ, const float* __restrict__ phiK,
                           const float* __restrict__ Vm, float* __restrict__ mv) {
    __shared__ float pkT[E_ * 17];
    __shared__ float sV[M_ * D_];
    __shared__ float pq[4][D_];
    __shared__ float sa[4][M_];
    int tid = threadIdx.x;
    for (int i = tid; i < M_ * E_; i += 256) {
        int m = i >> 6, e = i & 63;
        pkT[e * 17 + m] = phiK[m * E_ + e];
    }
    for (int i = tid; i < M_ * D_; i += 256) sV[i] = Vm[i];
    __syncthreads();
    int w = tid >> 6, lane = tid & 63;
    int b = blockIdx.x >> 8;
    int n = (blockIdx.x & 255) * 4 + w;
    int m = lane & 15, c = lane >> 4;
    float mvacc = 0.f;
    for (int t = 0; t < T_; ++t) {
        size_t rowoff = ((size_t)(b * T_ + t) * N_ + n) * 64;
        pq[w][lane] = phiQ[rowoff + lane];
        __syncthreads();
        float s = 0.f;
#pragma unroll
        for (int i = 0; i < 16; ++i) {
            int e = c * 16 + i;
            s += pq[w][e] * pkT[e * 17 + m];
        }
        s += __shfl_xor(s, 16, 64);
        s += __shfl_xor(s, 32, 64);
        s *= 0.125f;
        float mx = s;
        mx = fmaxf(mx, __shfl_xor(mx, 1, 64)); mx = fmaxf(mx, __shfl_xor(mx, 2, 64));
        mx = fmaxf(mx, __shfl_xor(mx, 4, 64)); mx = fmaxf(mx, __shfl_xor(mx, 8, 64));
        float ex = __expf(s - mx);
        float sum = ex;
        sum += __shfl_xor(sum, 1, 64); sum += __shfl_xor(sum, 2, 64);
        sum += __shfl_xor(sum, 4, 64); sum += __shfl_xor(sum, 8, 64);
        float a = ex / sum;
        if (lane < 16) sa[w][lane] = a;
        __syncthreads();
        float mval = 0.f;
#pragma unroll
        for (int mm = 0; mm < 16; ++mm) mval += sa[w][mm] * sV[mm * D_ + lane];
        mvacc += mval;
        __syncthreads();
    }
    mv[((size_t)b * N_ + n) * 64 + lane] = mvacc * (1.0f / 12.0f);
}

// ---------- K2b: BUF0 = phiQ @ KtV + H ----------
__global__ void k_matt(float* __restrict__ buf, const float* __restrict__ KtV,
                       const float* __restrict__ H) {
    __shared__ __align__(16) float AsT[64 * PAD];
    __shared__ __align__(16) float Bs[64 * PAD];
    int tid = threadIdx.x;
    float* rows = buf + (size_t)blockIdx.x * 4096;
    stageT(rows, 64, AsT, tid);
    stageN(KtV, 64, Bs, tid);
    __syncthreads();
    int ty = tid >> 4, tx = tid & 15;
    float acc[4][4] = {};
    mac64(AsT, Bs, acc, ty, tx);
    const float* hrow = H + (size_t)blockIdx.x * 4096;
#pragma unroll
    for (int i = 0; i < 4; ++i) {
        float4 h = *(const float4*)(hrow + (size_t)(ty * 4 + i) * 64 + tx * 4);
        float4 o;
        o.x = acc[i][0] + h.x; o.y = acc[i][1] + h.y;
        o.z = acc[i][2] + h.z; o.w = acc[i][3] + h.w;
        *(float4*)(rows + (size_t)(ty * 4 + i) * 64 + tx * 4) = o;
    }
}

// ---------- K3: H' = LN(BUF0 @ outW^T + outb), emit bf16 natural + transposed ----------
__global__ void k_outln(const float* __restrict__ buf, const float* __restrict__ outW,
                        const float* __restrict__ outb, const float* __restrict__ g,
                        const float* __restrict__ bb, __bf16* __restrict__ Hn,
                        __bf16* __restrict__ Ht) {
    __shared__ __align__(16) float AsT[64 * PAD];
    __shared__ __align__(16) float Bs[64 * PAD];
    int tid = threadIdx.x;
    const float* rows = buf + (size_t)blockIdx.x * 4096;
    stageT(rows, 64, AsT, tid);
    stageT(outW, 64, Bs, tid);
    __syncthreads();
    int ty = tid >> 4, tx = tid & 15;
    float acc[4][4] = {};
    mac64(AsT, Bs, acc, ty, tx);
    __syncthreads();                       // Bs will be reused as bf16 Cs
    __bf16* Cs = (__bf16*)Bs;
    float gg[4], bbv[4], bi[4];
#pragma unroll
    for (int j = 0; j < 4; ++j) {
        int o = tx * 4 + j;
        gg[j] = g[o]; bbv[j] = bb[o]; bi[j] = outb[o];
    }
    size_t base = (size_t)blockIdx.x * 4096;
#pragma unroll
    for (int i = 0; i < 4; ++i) {
        float v[4];
#pragma unroll
        for (int j = 0; j < 4; ++j) v[j] = acc[i][j] + bi[j];
        float s = v[0] + v[1] + v[2] + v[3];
        s += __shfl_xor(s, 1, 64); s += __shfl_xor(s, 2, 64);
        s += __shfl_xor(s, 4, 64); s += __shfl_xor(s, 8, 64);
        float mu = s * (1.0f / 64.0f);
        float qv = 0.f;
#pragma unroll
        for (int j = 0; j < 4; ++j) { float d = v[j] - mu; qv += d * d; }
        qv += __shfl_xor(qv, 1, 64); qv += __shfl_xor(qv, 2, 64);
        qv += __shfl_xor(qv, 4, 64); qv += __shfl_xor(qv, 8, 64);
        float rstd = rsqrtf(qv * (1.0f / 64.0f) + 1e-5f);
        int row = ty * 4 + i;
        bf16x4 ob;
#pragma unroll
        for (int j = 0; j < 4; ++j) {
            float o = (v[j] - mu) * rstd * gg[j] + bbv[j];
            ob[j] = (__bf16)o;
            Cs[row * DPAD + tx * 4 + j] = (__bf16)o;
        }
        *(bf16x4*)(Hn + base + (size_t)row * 64 + tx * 4) = ob;
    }
    __syncthreads();
    // transposed write: Ht[bt][d][n0+..]
    int bt = blockIdx.x >> 4;
    int n0 = (blockIdx.x & 15) * 64;
    size_t tbase = (size_t)bt * 64 * N_;
#pragma unroll
    for (int i = 0; i < 2; ++i) {
        int d = (tid >> 3) + i * 32;
        int n8 = (tid & 7) * 8;
        bf16x8 v;
#pragma unroll
        for (int j = 0; j < 8; ++j) {
            int jj = (j + tid) & 7;            // stagger to break bank conflicts
            v[jj] = Cs[(n8 + jj) * DPAD + d];
        }
        *(bf16x8*)(Ht + tbase + (size_t)d * N_ + n0 + n8) = v;
    }
}

// ---------- K4: A_dynamic + A_fused (fp32 out) + A_fused bf16 ----------
__global__ void k_adyn(const float* __restrict__ mv, const float* __restrict__ Ast,
                       const float* __restrict__ dinv, const float* __restrict__ beta,
                       float* __restrict__ Adyn, float* __restrict__ Afu,
                       __bf16* __restrict__ Afb) {
    __shared__ __align__(16) float mvn[8][PAD];
    __shared__ __align__(16) float tile[64][PAD];
    int tid = threadIdx.x;
    int b = blockIdx.x >> 7, n0 = (blockIdx.x & 127) * 8;
    const float* mvb = mv + (size_t)b * N_ * 64;
    for (int i = tid; i < 512; i += 256) {
        int r = i >> 6, d = i & 63;
        mvn[r][d] = mvb[(size_t)(n0 + r) * 64 + d];
    }
    __syncthreads();
    int nl = tid >> 5;
    int mi = tid & 31;
    float s[32];
    for (int mt = 0; mt < 16; ++mt) {
        if (mt) __syncthreads();
        for (int i = tid; i < 4096; i += 256) {
            int r = i >> 6, d = i & 63;
            tile[r][d] = mvb[(size_t)(mt * 64 + r) * 64 + d];
        }
        __syncthreads();
#pragma unroll
        for (int j = 0; j < 2; ++j) {
            int ml = mi + 32 * j;
            float dot = 0.f;
#pragma unroll
            for (int k4 = 0; k4 < 16; ++k4) {
                float4 x = *(const float4*)&mvn[nl][k4 * 4];
                float4 y = *(const float4*)&tile[ml][k4 * 4];
                dot += x.x * y.x + x.y * y.y + x.z * y.z + x.w * y.w;
            }
            s[mt * 2 + j] = dot * 0.125f;
        }
    }
    float mx = -3.4e38f;
#pragma unroll
    for (int i = 0; i < 32; ++i) mx = fmaxf(mx, s[i]);
    mx = fmaxf(mx, __shfl_xor(mx, 1, 64));  mx = fmaxf(mx, __shfl_xor(mx, 2, 64));
    mx = fmaxf(mx, __shfl_xor(mx, 4, 64));  mx = fmaxf(mx, __shfl_xor(mx, 8, 64));
    mx = fmaxf(mx, __shfl_xor(mx, 16, 64));
    float sum = 0.f;
#pragma unroll
    for (int i = 0; i < 32; ++i) { s[i] = __expf(s[i] - mx); sum += s[i]; }
    sum += __shfl_xor(sum, 1, 64);  sum += __shfl_xor(sum, 2, 64);
    sum += __shfl_xor(sum, 4, 64);  sum += __shfl_xor(sum, 8, 64);
    sum += __shfl_xor(sum, 16, 64);
    float inv = 1.0f / sum;
    float bta = fminf(fmaxf(beta[0], 0.0f), 1.0f);
    int n = n0 + nl;
    float dn = dinv[n];
    size_t rowo = ((size_t)b * N_ + n) * N_;
#pragma unroll
    for (int i = 0; i < 32; ++i) {
        int m = (i >> 1) * 64 + (i & 1) * 32 + mi;
        float ad = s[i] * inv;
        float fu = bta * ad + (1.0f - bta) * dn * Ast[(size_t)n * N_ + m] * dinv[m];
        Adyn[rowo + m] = ad;
        Afu[rowo + m] = fu;
        Afb[rowo + m] = (__bf16)fu;
    }
}

// ---------- K5/K6: MFMA diffusion hop: Out[n][d] = sum_m A[n][m] X[m][d] ----------
// A bf16 natural [n][m]; X bf16 TRANSPOSED [d][m] so B-fragments are contiguous in k=m.
// BM=128, BN=64, BK=64; 4 waves, each 32 rows (2x 16x16 row-tiles, 4 col-tiles).
__global__ void k_diffuse_mfma(const __bf16* __restrict__ Afb, const __bf16* __restrict__ Xt,
                               __bf16* __restrict__ Xn_out, __bf16* __restrict__ Xt_out) {
    __shared__ __align__(16) __bf16 As[128 * DPAD];
    __shared__ __align__(16) __bf16 Bs[64 * DPAD];
    int tid = threadIdx.x;
    int bt = blockIdx.y, b = bt / T_;
    int n0 = blockIdx.x * 128;
    const __bf16* A = Afb + (size_t)b * N_ * N_ + (size_t)n0 * N_;
    const __bf16* X = Xt + (size_t)bt * 64 * N_;
    int w = tid >> 6, lane = tid & 63, q = lane >> 4, lr = lane & 15;
    int mw = w * 32;
    f32x4 acc[2][4];
#pragma unroll
    for (int i = 0; i < 2; ++i)
#pragma unroll
        for (int j = 0; j < 4; ++j) acc[i][j] = (f32x4)(0.0f);
    int arow = tid >> 3, acol = (tid & 7) * 8;
    for (int kc = 0; kc < 16; ++kc) {
        if (kc) __syncthreads();
#pragma unroll
        for (int i = 0; i < 4; ++i) {
            int r = arow + i * 32;
            *(bf16x8*)&As[r * DPAD + acol] = *(const bf16x8*)(A + (size_t)r * N_ + kc * 64 + acol);
        }
#pragma unroll
        for (int i = 0; i < 2; ++i) {
            int r = arow + i * 32;
            *(bf16x8*)&Bs[r * DPAD + acol] = *(const bf16x8*)(X + (size_t)r * N_ + kc * 64 + acol);
        }
        __syncthreads();
#pragma unroll
        for (int ks = 0; ks < 2; ++ks) {
            int kb = ks * 32 + q * 8;
            bf16x8 a0 = *(const bf16x8*)&As[(mw + lr) * DPAD + kb];
            bf16x8 a1 = *(const bf16x8*)&As[(mw + 16 + lr) * DPAD + kb];
#pragma unroll
            for (int tj = 0; tj < 4; ++tj) {
                bf16x8 bf = *(const bf16x8*)&Bs[(tj * 16 + lr) * DPAD + kb];
                acc[0][tj] = __builtin_amdgcn_mfma_f32_16x16x32_bf16(a0, bf, acc[0][tj], 0, 0, 0);
                acc[1][tj] = __builtin_amdgcn_mfma_f32_16x16x32_bf16(a1, bf, acc[1][tj], 0, 0, 0);
            }
        }
    }
    __syncthreads();
    // dump accumulators (C/D layout: row = quad*4+reg, col = lane&15) to LDS as bf16
    __bf16* Cs = As;
#pragma unroll
    for (int ti = 0; ti < 2; ++ti)
#pragma unroll
        for (int tj = 0; tj < 4; ++tj)
#pragma unroll
            for (int r = 0; r < 4; ++r)
                Cs[(mw + ti * 16 + q * 4 + r) * DPAD + tj * 16 + lr] = (__bf16)acc[ti][tj][r];
    __syncthreads();
    size_t obase = (size_t)bt * N_ * 64;
#pragma unroll
    for (int i = 0; i < 4; ++i) {
        int r = arow + i * 32;
        *(bf16x8*)(Xn_out + obase + (size_t)(n0 + r) * 64 + acol) = *(const bf16x8*)&Cs[r * DPAD + acol];
    }
    if (Xt_out) {
        size_t tbase = (size_t)bt * 64 * N_;
#pragma unroll
        for (int i = 0; i < 4; ++i) {
            int d = (tid >> 4) + i * 16;
            int n8 = (tid & 15) * 8;
            bf16x8 v;
#pragma unroll
            for (int j = 0; j < 8; ++j) {
                int jj = (j + tid) & 7;        // stagger to break bank conflicts
                v[jj] = Cs[(n8 + jj) * DPAD + d];
            }
            *(bf16x8*)(Xt_out + tbase + (size_t)d * N_ + n0 + n8) = v;
        }
    }
}

// ---------- K7: MFMA proj + LN: out = LN(cat(H',X1,X2) @ PW^T + pb) ----------
__global__ void k_projln_mfma(const __bf16* __restrict__ Hn, const __bf16* __restrict__ X1n,
                              const __bf16* __restrict__ X2n, const float* __restrict__ PW,
                              const float* __restrict__ pb, const float* __restrict__ g,
                              const float* __restrict__ bb, float* __restrict__ out) {
    __shared__ __align__(16) __bf16 As[128 * DPAD];
    __shared__ __align__(16) __bf16 Bs[64 * DPAD];
    int tid = threadIdx.x;
    size_t r0 = (size_t)blockIdx.x * 128;
    int w = tid >> 6, lane = tid & 63, q = lane >> 4, lr = lane & 15;
    int mw = w * 32;
    f32x4 acc[2][4];
#pragma unroll
    for (int i = 0; i < 2; ++i)
#pragma unroll
        for (int j = 0; j < 4; ++j) acc[i][j] = (f32x4)(0.0f);
    const __bf16* srcs[3] = {Hn, X1n, X2n};
    int arow = tid >> 3, acol = (tid & 7) * 8;
    int prow = tid >> 2, pc16 = (tid & 3) * 16;
    for (int c = 0; c < 3; ++c) {
        if (c) __syncthreads();
        const __bf16* S = srcs[c] + r0 * 64;
#pragma unroll
        for (int i = 0; i < 4; ++i) {
            int r = arow + i * 32;
            *(bf16x8*)&As[r * DPAD + acol] = *(const bf16x8*)(S + (size_t)r * 64 + acol);
        }
        // stage PW chunk as B: Bs[o][cc] = PW[o][c*64+cc]  (fragment reads contiguous in k=c)
        const float* P = PW + (size_t)prow * 192 + c * 64 + pc16;
        float4 f0 = *(const float4*)(P + 0);
        float4 f1 = *(const float4*)(P + 4);
        float4 f2 = *(const float4*)(P + 8);
        float4 f3 = *(const float4*)(P + 12);
        bf16x8 w0, w1;
        w0[0] = (__bf16)f0.x; w0[1] = (__bf16)f0.y; w0[2] = (__bf16)f0.z; w0[3] = (__bf16)f0.w;
        w0[4] = (__bf16)f1.x; w0[5] = (__bf16)f1.y; w0[6] = (__bf16)f1.z; w0[7] = (__bf16)f1.w;
        w1[0] = (__bf16)f2.x; w1[1] = (__bf16)f2.y; w1[2] = (__bf16)f2.z; w1[3] = (__bf16)f2.w;
        w1[4] = (__bf16)f3.x; w1[5] = (__bf16)f3.y; w1[6] = (__bf16)f3.z; w1[7] = (__bf16)f3.w;
        *(bf16x8*)&Bs[prow * DPAD + pc16] = w0;
        *(bf16x8*)&Bs[prow * DPAD + pc16 + 8] = w1;
        __syncthreads();
#pragma unroll
        for (int ks = 0; ks < 2; ++ks) {
            int kb = ks * 32 + q * 8;
            bf16x8 a0 = *(const bf16x8*)&As[(mw + lr) * DPAD + kb];
            bf16x8 a1 = *(const bf16x8*)&As[(mw + 16 + lr) * DPAD + kb];
#pragma unroll
            for (int tj = 0; tj < 4; ++tj) {
                bf16x8 bf = *(const bf16x8*)&Bs[(tj * 16 + lr) * DPAD + kb];
                acc[0][tj] = __builtin_amdgcn_mfma_f32_16x16x32_bf16(a0, bf, acc[0][tj], 0, 0, 0);
                acc[1][tj] = __builtin_amdgcn_mfma_f32_16x16x32_bf16(a1, bf, acc[1][tj], 0, 0, 0);
            }
        }
    }
    // epilogue: bias + LN over 64 cols (cols = tj*16 + lr), rows = mw + ti*16 + q*4 + r
    float pbv[4], gv[4], bv2[4];
#pragma unroll
    for (int tj = 0; tj < 4; ++tj) {
        int col = tj * 16 + lr;
        pbv[tj] = pb[col]; gv[tj] = g[col]; bv2[tj] = bb[col];
    }
#pragma unroll
    for (int ti = 0; ti < 2; ++ti) {
#pragma unroll
        for (int r = 0; r < 4; ++r) {
            float v[4];
            float s = 0.f;
#pragma unroll
            for (int tj = 0; tj < 4; ++tj) { v[tj] = acc[ti][tj][r] + pbv[tj]; s += v[tj]; }
            s += __shfl_xor(s, 1, 64); s += __shfl_xor(s, 2, 64);
            s += __shfl_xor(s, 4, 64); s += __shfl_xor(s, 8, 64);
            float mu = s * (1.0f / 64.0f);
            float qv = 0.f;
#pragma unroll
            for (int tj = 0; tj < 4; ++tj) { float d = v[tj] - mu; qv += d * d; }
            qv += __shfl_xor(qv, 1, 64); qv += __shfl_xor(qv, 2, 64);
            qv += __shfl_xor(qv, 4, 64); qv += __shfl_xor(qv, 8, 64);
            float rstd = rsqrtf(qv * (1.0f / 64.0f) + 1e-5f);
            size_t row = r0 + mw + ti * 16 + q * 4 + r;
#pragma unroll
            for (int tj = 0; tj < 4; ++tj)
                out[row * 64 + tj * 16 + lr] = (v[tj] - mu) * rstd * gv[tj] + bv2[tj];
        }
    }
}

// ---------- launch ----------
extern "C" void kernel_launch(void* const* d_in, const int* in_sizes, int n_in,
                              void* d_out, int out_size, void* d_ws, size_t ws_size,
                              hipStream_t stream) {
    const float* H    = (const float*)d_in[0];
    const float* Ast  = (const float*)d_in[1];
    const float* WQ   = (const float*)d_in[2];
    const float* WK   = (const float*)d_in[3];
    const float* WV   = (const float*)d_in[4];
    const float* PHI  = (const float*)d_in[5];
    const float* outW = (const float*)d_in[6];
    const float* outb = (const float*)d_in[7];
    const float* smag = (const float*)d_in[8];
    const float* smab = (const float*)d_in[9];
    const float* beta = (const float*)d_in[10];
    const float* PW   = (const float*)d_in[11];
    const float* pb   = (const float*)d_in[12];
    const float* aggg = (const float*)d_in[13];
    const float* aggb = (const float*)d_in[14];

    float* out  = (float*)d_out;
    float* Hsp  = out;
    float* Adyn = out + (size_t)ROWS_ * 64;
    float* Afu  = Adyn + (size_t)B_ * N_ * N_;

    float* ws   = (float*)d_ws;
    float* BUF0 = ws;                                  // fp32 phiQ -> Hp (dead after outln)
    float* mv   = ws + (size_t)ROWS_ * 64;
    float* phiK = mv + (size_t)B_ * N_ * 64;
    float* Vm   = phiK + M_ * E_;
    float* KtV  = Vm + M_ * D_;
    float* dinv = KtV + E_ * D_;
    __bf16* Hn  = (__bf16*)(dinv + N_);                // H' natural bf16
    __bf16* Ht  = Hn + (size_t)ROWS_ * 64;             // H' transposed bf16 (dead after hop1)
    __bf16* Afb = Ht + (size_t)ROWS_ * 64;             // A_fused bf16
    __bf16* X1n = (__bf16*)BUF0;                       // alias dead BUF0 region
    __bf16* X1t = X1n + (size_t)ROWS_ * 64;
    __bf16* X2n = Ht;                                  // alias dead Ht region

    k_precompute<<<1, 256, 0, stream>>>(PHI, WK, WV, phiK, Vm, KtV);
    k_dinv<<<N_, 256, 0, stream>>>(Ast, dinv);
    k_phiq<<<ROWS_ / 64, 256, 0, stream>>>(H, WQ, BUF0);
    k_attn_mem<<<B_ * N_ / 4, 256, 0, stream>>>(BUF0, phiK, Vm, mv);
    k_matt<<<ROWS_ / 64, 256, 0, stream>>>(BUF0, KtV, H);
    k_outln<<<ROWS_ / 64, 256, 0, stream>>>(BUF0, outW, outb, smag, smab, Hn, Ht);
    k_adyn<<<B_ * N_ / 8, 256, 0, stream>>>(mv, Ast, dinv, beta, Adyn, Afu, Afb);
    k_diffuse_mfma<<<dim3(8, BT_), 256, 0, stream>>>(Afb, Ht, X1n, X1t);
    k_diffuse_mfma<<<dim3(8, BT_), 256, 0, stream>>>(Afb, X1t, X2n, (__bf16*)nullptr);
    k_projln_mfma<<<ROWS_ / 128, 256, 0, stream>>>(Hn, X1n, X2n, PW, pb, aggg, aggb, Hsp);
}

// Round 3
// 320.363 us; speedup vs baseline: 2.2703x; 1.2277x over previous
//
#include <hip/hip_runtime.h>
#include <math.h>

#define B_ 8
#define T_ 12
#define N_ 1024
#define D_ 64
#define E_ 64
#define M_ 16
#define BT_ (B_*T_)
#define ROWS_ (B_*T_*N_)
#define PAD 68    // fp32 LDS pitch (272 B)
#define DPAD 72   // bf16 LDS pitch (144 B): 16B-aligned rows, +4-bank rotation/row

typedef __attribute__((ext_vector_type(8))) __bf16 bf16x8;
typedef __attribute__((ext_vector_type(4))) __bf16 bf16x4;
typedef __attribute__((ext_vector_type(4))) float f32x4;

__device__ __forceinline__ float elu1(float x) {
    return x > 0.0f ? x + 1.0f : __expf(x);
}

// ---------- fp32 tile helpers (64x64 tiles, 256 threads) ----------

__device__ __forceinline__ void stageT(const float* __restrict__ src, int stride,
                                       float* __restrict__ lds, int tid) {
#pragma unroll
    for (int i = 0; i < 16; ++i) {
        int idx = tid + i * 256;
        int r = idx >> 6, c = idx & 63;
        lds[c * PAD + r] = src[r * stride + c];
    }
}

__device__ __forceinline__ void stageN(const float* __restrict__ src, int stride,
                                       float* __restrict__ lds, int tid) {
#pragma unroll
    for (int i = 0; i < 16; ++i) {
        int idx = tid + i * 256;
        int r = idx >> 6, c = idx & 63;
        lds[r * PAD + c] = src[r * stride + c];
    }
}

__device__ __forceinline__ void mac64(const float* __restrict__ AsT, const float* __restrict__ Bs,
                                      float acc[4][4], int ty, int tx) {
#pragma unroll 8
    for (int k = 0; k < 64; ++k) {
        float4 a = *(const float4*)(AsT + k * PAD + ty * 4);
        float4 b = *(const float4*)(Bs + k * PAD + tx * 4);
        float av[4] = {a.x, a.y, a.z, a.w};
        float bv[4] = {b.x, b.y, b.z, b.w};
#pragma unroll
        for (int i = 0; i < 4; ++i)
#pragma unroll
            for (int j = 0; j < 4; ++j)
                acc[i][j] = fmaf(av[i], bv[j], acc[i][j]);
    }
}

// ---------- K0a ----------
__global__ void k_precompute(const float* __restrict__ PHI, const float* __restrict__ WK,
                             const float* __restrict__ WV, float* __restrict__ phiK,
                             float* __restrict__ Vm, float* __restrict__ KtV) {
    __shared__ float sPhiK[M_ * E_];
    __shared__ float sV[M_ * D_];
    int tid = threadIdx.x;
    for (int i = tid; i < M_ * E_; i += 256) {
        int m = i >> 6, e = i & 63;
        float kk = 0.f, vv = 0.f;
        for (int j = 0; j < E_; ++j) {
            float p = PHI[m * E_ + j];
            kk += p * WK[e * E_ + j];
            vv += p * WV[e * E_ + j];
        }
        float pk = elu1(kk);
        sPhiK[i] = pk; phiK[i] = pk;
        sV[i] = vv;    Vm[i] = vv;
    }
    __syncthreads();
    for (int i = tid; i < E_ * D_; i += 256) {
        int e = i >> 6, d = i & 63;
        float acc = 0.f;
        for (int m = 0; m < M_; ++m) acc += sPhiK[m * E_ + e] * sV[m * D_ + d];
        KtV[i] = acc;
    }
}

// ---------- K0b ----------
__global__ void k_dinv(const float* __restrict__ A, float* __restrict__ dinv) {
    int row = blockIdx.x;
    int tid = threadIdx.x;
    float s = 0.f;
    for (int i = tid; i < N_; i += 256) s += A[(size_t)row * N_ + i];
    for (int off = 32; off; off >>= 1) s += __shfl_xor(s, off, 64);
    __shared__ float red[4];
    if ((tid & 63) == 0) red[tid >> 6] = s;
    __syncthreads();
    if (tid == 0) dinv[row] = rsqrtf(red[0] + red[1] + red[2] + red[3] + 1e-12f);
}

// ---------- K1: phiQ ----------
__global__ void k_phiq(const float* __restrict__ H, const float* __restrict__ WQ,
                       float* __restrict__ out) {
    __shared__ __align__(16) float AsT[64 * PAD];
    __shared__ __align__(16) float Bs[64 * PAD];
    int tid = threadIdx.x;
    const float* Arow = H + (size_t)blockIdx.x * 4096;
    stageT(Arow, 64, AsT, tid);
    stageT(WQ, 64, Bs, tid);
    __syncthreads();
    int ty = tid >> 4, tx = tid & 15;
    float acc[4][4] = {};
    mac64(AsT, Bs, acc, ty, tx);
    float* orow = out + (size_t)blockIdx.x * 4096;
#pragma unroll
    for (int i = 0; i < 4; ++i) {
        float4 o;
        o.x = elu1(acc[i][0]); o.y = elu1(acc[i][1]);
        o.z = elu1(acc[i][2]); o.w = elu1(acc[i][3]);
        *(float4*)(orow + (size_t)(ty * 4 + i) * 64 + tx * 4) = o;
    }
}

// ---------- K2a: memory-slot softmax, mem_val, t-mean -> mv (bf16 out) ----------
__global__ void k_attn_mem(const float* __restrict__ phiQ, const float* __restrict__ phiK,
                           const float* __restrict__ Vm, __bf16* __restrict__ mv) {
    __shared__ float pkT[E_ * 17];
    __shared__ float sV[M_ * D_];
    __shared__ float pq[4][D_];
    __shared__ float sa[4][M_];
    int tid = threadIdx.x;
    for (int i = tid; i < M_ * E_; i += 256) {
        int m = i >> 6, e = i & 63;
        pkT[e * 17 + m] = phiK[m * E_ + e];
    }
    for (int i = tid; i < M_ * D_; i += 256) sV[i] = Vm[i];
    __syncthreads();
    int w = tid >> 6, lane = tid & 63;
    int b = blockIdx.x >> 8;
    int n = (blockIdx.x & 255) * 4 + w;
    int m = lane & 15, c = lane >> 4;
    float mvacc = 0.f;
    for (int t = 0; t < T_; ++t) {
        size_t rowoff = ((size_t)(b * T_ + t) * N_ + n) * 64;
        pq[w][lane] = phiQ[rowoff + lane];
        __syncthreads();
        float s = 0.f;
#pragma unroll
        for (int i = 0; i < 16; ++i) {
            int e = c * 16 + i;
            s += pq[w][e] * pkT[e * 17 + m];
        }
        s += __shfl_xor(s, 16, 64);
        s += __shfl_xor(s, 32, 64);
        s *= 0.125f;
        float mx = s;
        mx = fmaxf(mx, __shfl_xor(mx, 1, 64)); mx = fmaxf(mx, __shfl_xor(mx, 2, 64));
        mx = fmaxf(mx, __shfl_xor(mx, 4, 64)); mx = fmaxf(mx, __shfl_xor(mx, 8, 64));
        float ex = __expf(s - mx);
        float sum = ex;
        sum += __shfl_xor(sum, 1, 64); sum += __shfl_xor(sum, 2, 64);
        sum += __shfl_xor(sum, 4, 64); sum += __shfl_xor(sum, 8, 64);
        float a = ex / sum;
        if (lane < 16) sa[w][lane] = a;
        __syncthreads();
        float mval = 0.f;
#pragma unroll
        for (int mm = 0; mm < 16; ++mm) mval += sa[w][mm] * sV[mm * D_ + lane];
        mvacc += mval;
        __syncthreads();
    }
    mv[((size_t)b * N_ + n) * 64 + lane] = (__bf16)(mvacc * (1.0f / 12.0f));
}

// ---------- K2b: BUF0 = phiQ @ KtV + H ----------
__global__ void k_matt(float* __restrict__ buf, const float* __restrict__ KtV,
                       const float* __restrict__ H) {
    __shared__ __align__(16) float AsT[64 * PAD];
    __shared__ __align__(16) float Bs[64 * PAD];
    int tid = threadIdx.x;
    float* rows = buf + (size_t)blockIdx.x * 4096;
    stageT(rows, 64, AsT, tid);
    stageN(KtV, 64, Bs, tid);
    __syncthreads();
    int ty = tid >> 4, tx = tid & 15;
    float acc[4][4] = {};
    mac64(AsT, Bs, acc, ty, tx);
    const float* hrow = H + (size_t)blockIdx.x * 4096;
#pragma unroll
    for (int i = 0; i < 4; ++i) {
        float4 h = *(const float4*)(hrow + (size_t)(ty * 4 + i) * 64 + tx * 4);
        float4 o;
        o.x = acc[i][0] + h.x; o.y = acc[i][1] + h.y;
        o.z = acc[i][2] + h.z; o.w = acc[i][3] + h.w;
        *(float4*)(rows + (size_t)(ty * 4 + i) * 64 + tx * 4) = o;
    }
}

// ---------- K3: H' = LN(BUF0 @ outW^T + outb), emit bf16 natural + transposed ----------
__global__ void k_outln(const float* __restrict__ buf, const float* __restrict__ outW,
                        const float* __restrict__ outb, const float* __restrict__ g,
                        const float* __restrict__ bb, __bf16* __restrict__ Hn,
                        __bf16* __restrict__ Ht) {
    __shared__ __align__(16) float AsT[64 * PAD];
    __shared__ __align__(16) float Bs[64 * PAD];
    int tid = threadIdx.x;
    const float* rows = buf + (size_t)blockIdx.x * 4096;
    stageT(rows, 64, AsT, tid);
    stageT(outW, 64, Bs, tid);
    __syncthreads();
    int ty = tid >> 4, tx = tid & 15;
    float acc[4][4] = {};
    mac64(AsT, Bs, acc, ty, tx);
    __syncthreads();                       // Bs will be reused as bf16 Cs
    __bf16* Cs = (__bf16*)Bs;
    float gg[4], bbv[4], bi[4];
#pragma unroll
    for (int j = 0; j < 4; ++j) {
        int o = tx * 4 + j;
        gg[j] = g[o]; bbv[j] = bb[o]; bi[j] = outb[o];
    }
    size_t base = (size_t)blockIdx.x * 4096;
#pragma unroll
    for (int i = 0; i < 4; ++i) {
        float v[4];
#pragma unroll
        for (int j = 0; j < 4; ++j) v[j] = acc[i][j] + bi[j];
        float s = v[0] + v[1] + v[2] + v[3];
        s += __shfl_xor(s, 1, 64); s += __shfl_xor(s, 2, 64);
        s += __shfl_xor(s, 4, 64); s += __shfl_xor(s, 8, 64);
        float mu = s * (1.0f / 64.0f);
        float qv = 0.f;
#pragma unroll
        for (int j = 0; j < 4; ++j) { float d = v[j] - mu; qv += d * d; }
        qv += __shfl_xor(qv, 1, 64); qv += __shfl_xor(qv, 2, 64);
        qv += __shfl_xor(qv, 4, 64); qv += __shfl_xor(qv, 8, 64);
        float rstd = rsqrtf(qv * (1.0f / 64.0f) + 1e-5f);
        int row = ty * 4 + i;
        bf16x4 ob;
#pragma unroll
        for (int j = 0; j < 4; ++j) {
            float o = (v[j] - mu) * rstd * gg[j] + bbv[j];
            ob[j] = (__bf16)o;
            Cs[row * DPAD + tx * 4 + j] = (__bf16)o;
        }
        *(bf16x4*)(Hn + base + (size_t)row * 64 + tx * 4) = ob;
    }
    __syncthreads();
    // transposed write: Ht[bt][d][n0+..]
    int bt = blockIdx.x >> 4;
    int n0 = (blockIdx.x & 15) * 64;
    size_t tbase = (size_t)bt * 64 * N_;
#pragma unroll
    for (int i = 0; i < 2; ++i) {
        int d = (tid >> 3) + i * 32;
        int n8 = (tid & 7) * 8;
        bf16x8 v;
#pragma unroll
        for (int j = 0; j < 8; ++j) {
            int jj = (j + tid) & 7;            // stagger to break bank conflicts
            v[jj] = Cs[(n8 + jj) * DPAD + d];
        }
        *(bf16x8*)(Ht + tbase + (size_t)d * N_ + n0 + n8) = v;
    }
}

// ---------- K4: MFMA A_dynamic + A_fused, flash-style in-register row softmax ----------
// Block: 16 rows x 1024 cols of S = mv@mv^T / 8 per batch b. 4 waves, wave w owns
// cols {c*256 + w*64 .. +63} for c=0..3. Scores live in 64 acc VGPRs/lane.
__global__ void k_adyn_mfma(const __bf16* __restrict__ mvb_all, const float* __restrict__ Ast,
                            const float* __restrict__ dinv, const float* __restrict__ beta,
                            float* __restrict__ Adyn, float* __restrict__ Afu,
                            __bf16* __restrict__ Afb) {
    __shared__ __align__(16) __bf16 As[16 * DPAD];
    __shared__ __align__(16) __bf16 Bs[256 * DPAD];
    __shared__ float redm[4][16];
    __shared__ float reds[4][16];
    int tid = threadIdx.x;
    int b = blockIdx.x >> 6, n0 = (blockIdx.x & 63) * 16;
    const __bf16* mvb = mvb_all + (size_t)b * N_ * 64;
    // stage A (16 rows x 64)
    {
        int r = tid >> 4, c4 = (tid & 15) * 4;
        *(bf16x4*)&As[r * DPAD + c4] = *(const bf16x4*)(mvb + (size_t)(n0 + r) * 64 + c4);
    }
    int w = tid >> 6, lane = tid & 63, q = lane >> 4, lr = lane & 15;
    f32x4 acc[4][4];
#pragma unroll
    for (int c = 0; c < 4; ++c)
#pragma unroll
        for (int tj = 0; tj < 4; ++tj) acc[c][tj] = (f32x4)(0.0f);
    int brow = tid >> 3, bcol = (tid & 7) * 8;
    for (int c = 0; c < 4; ++c) {
        __syncthreads();
#pragma unroll
        for (int i = 0; i < 8; ++i) {
            int r = brow + i * 32;
            *(bf16x8*)&Bs[r * DPAD + bcol] = *(const bf16x8*)(mvb + (size_t)(c * 256 + r) * 64 + bcol);
        }
        __syncthreads();
#pragma unroll
        for (int ks = 0; ks < 2; ++ks) {
            int kb = ks * 32 + q * 8;
            bf16x8 a0 = *(const bf16x8*)&As[lr * DPAD + kb];
#pragma unroll
            for (int tj = 0; tj < 4; ++tj) {
                bf16x8 bv = *(const bf16x8*)&Bs[(w * 64 + tj * 16 + lr) * DPAD + kb];
                acc[c][tj] = __builtin_amdgcn_mfma_f32_16x16x32_bf16(a0, bv, acc[c][tj], 0, 0, 0);
            }
        }
    }
    // ---- row-wise softmax over 1024 cols; lane holds rows q*4+rr, cols c*256+w*64+tj*16+lr
    float mrow[4];
#pragma unroll
    for (int rr = 0; rr < 4; ++rr) {
        float m = -3.4e38f;
#pragma unroll
        for (int c = 0; c < 4; ++c)
#pragma unroll
            for (int tj = 0; tj < 4; ++tj) m = fmaxf(m, acc[c][tj][rr]);
        m = fmaxf(m, __shfl_xor(m, 1, 64)); m = fmaxf(m, __shfl_xor(m, 2, 64));
        m = fmaxf(m, __shfl_xor(m, 4, 64)); m = fmaxf(m, __shfl_xor(m, 8, 64));
        mrow[rr] = m;
    }
    if (lr == 0) {
#pragma unroll
        for (int rr = 0; rr < 4; ++rr) redm[w][q * 4 + rr] = mrow[rr];
    }
    __syncthreads();
    float mg[4];
#pragma unroll
    for (int rr = 0; rr < 4; ++rr) {
        int row = q * 4 + rr;
        mg[rr] = fmaxf(fmaxf(redm[0][row], redm[1][row]), fmaxf(redm[2][row], redm[3][row]));
    }
    float srow[4] = {0.f, 0.f, 0.f, 0.f};
#pragma unroll
    for (int c = 0; c < 4; ++c)
#pragma unroll
        for (int tj = 0; tj < 4; ++tj)
#pragma unroll
            for (int rr = 0; rr < 4; ++rr) {
                float e = __expf(0.125f * (acc[c][tj][rr] - mg[rr]));
                acc[c][tj][rr] = e;
                srow[rr] += e;
            }
#pragma unroll
    for (int rr = 0; rr < 4; ++rr) {
        float s = srow[rr];
        s += __shfl_xor(s, 1, 64); s += __shfl_xor(s, 2, 64);
        s += __shfl_xor(s, 4, 64); s += __shfl_xor(s, 8, 64);
        srow[rr] = s;
    }
    if (lr == 0) {
#pragma unroll
        for (int rr = 0; rr < 4; ++rr) reds[w][q * 4 + rr] = srow[rr];
    }
    __syncthreads();
    float inv[4];
#pragma unroll
    for (int rr = 0; rr < 4; ++rr) {
        int row = q * 4 + rr;
        inv[rr] = 1.0f / (reds[0][row] + reds[1][row] + reds[2][row] + reds[3][row]);
    }
    float bta = fminf(fmaxf(beta[0], 0.0f), 1.0f);
    float omb = 1.0f - bta;
    float dc[4][4];
#pragma unroll
    for (int c = 0; c < 4; ++c)
#pragma unroll
        for (int tj = 0; tj < 4; ++tj) dc[c][tj] = dinv[c * 256 + w * 64 + tj * 16 + lr];
#pragma unroll
    for (int rr = 0; rr < 4; ++rr) {
        int n = n0 + q * 4 + rr;
        float dn = omb * dinv[n];
        size_t ro = ((size_t)b * N_ + n) * N_;
        const float* arow = Ast + (size_t)n * N_;
#pragma unroll
        for (int c = 0; c < 4; ++c)
#pragma unroll
            for (int tj = 0; tj < 4; ++tj) {
                int col = c * 256 + w * 64 + tj * 16 + lr;
                float p = acc[c][tj][rr] * inv[rr];
                float fu = bta * p + dn * arow[col] * dc[c][tj];
                Adyn[ro + col] = p;
                Afu[ro + col] = fu;
                Afb[ro + col] = (__bf16)fu;
            }
    }
}

// ---------- K5/K6: MFMA diffusion hop: Out[n][d] = sum_m A[n][m] X[m][d] ----------
__global__ void k_diffuse_mfma(const __bf16* __restrict__ Afb, const __bf16* __restrict__ Xt,
                               __bf16* __restrict__ Xn_out, __bf16* __restrict__ Xt_out) {
    __shared__ __align__(16) __bf16 As[128 * DPAD];
    __shared__ __align__(16) __bf16 Bs[64 * DPAD];
    int tid = threadIdx.x;
    int bt = blockIdx.y, b = bt / T_;
    int n0 = blockIdx.x * 128;
    const __bf16* A = Afb + (size_t)b * N_ * N_ + (size_t)n0 * N_;
    const __bf16* X = Xt + (size_t)bt * 64 * N_;
    int w = tid >> 6, lane = tid & 63, q = lane >> 4, lr = lane & 15;
    int mw = w * 32;
    f32x4 acc[2][4];
#pragma unroll
    for (int i = 0; i < 2; ++i)
#pragma unroll
        for (int j = 0; j < 4; ++j) acc[i][j] = (f32x4)(0.0f);
    int arow = tid >> 3, acol = (tid & 7) * 8;
    for (int kc = 0; kc < 16; ++kc) {
        if (kc) __syncthreads();
#pragma unroll
        for (int i = 0; i < 4; ++i) {
            int r = arow + i * 32;
            *(bf16x8*)&As[r * DPAD + acol] = *(const bf16x8*)(A + (size_t)r * N_ + kc * 64 + acol);
        }
#pragma unroll
        for (int i = 0; i < 2; ++i) {
            int r = arow + i * 32;
            *(bf16x8*)&Bs[r * DPAD + acol] = *(const bf16x8*)(X + (size_t)r * N_ + kc * 64 + acol);
        }
        __syncthreads();
#pragma unroll
        for (int ks = 0; ks < 2; ++ks) {
            int kb = ks * 32 + q * 8;
            bf16x8 a0 = *(const bf16x8*)&As[(mw + lr) * DPAD + kb];
            bf16x8 a1 = *(const bf16x8*)&As[(mw + 16 + lr) * DPAD + kb];
#pragma unroll
            for (int tj = 0; tj < 4; ++tj) {
                bf16x8 bf = *(const bf16x8*)&Bs[(tj * 16 + lr) * DPAD + kb];
                acc[0][tj] = __builtin_amdgcn_mfma_f32_16x16x32_bf16(a0, bf, acc[0][tj], 0, 0, 0);
                acc[1][tj] = __builtin_amdgcn_mfma_f32_16x16x32_bf16(a1, bf, acc[1][tj], 0, 0, 0);
            }
        }
    }
    __syncthreads();
    __bf16* Cs = As;
#pragma unroll
    for (int ti = 0; ti < 2; ++ti)
#pragma unroll
        for (int tj = 0; tj < 4; ++tj)
#pragma unroll
            for (int r = 0; r < 4; ++r)
                Cs[(mw + ti * 16 + q * 4 + r) * DPAD + tj * 16 + lr] = (__bf16)acc[ti][tj][r];
    __syncthreads();
    size_t obase = (size_t)bt * N_ * 64;
#pragma unroll
    for (int i = 0; i < 4; ++i) {
        int r = arow + i * 32;
        *(bf16x8*)(Xn_out + obase + (size_t)(n0 + r) * 64 + acol) = *(const bf16x8*)&Cs[r * DPAD + acol];
    }
    if (Xt_out) {
        size_t tbase = (size_t)bt * 64 * N_;
#pragma unroll
        for (int i = 0; i < 4; ++i) {
            int d = (tid >> 4) + i * 16;
            int n8 = (tid & 15) * 8;
            bf16x8 v;
#pragma unroll
            for (int j = 0; j < 8; ++j) {
                int jj = (j + tid) & 7;        // stagger to break bank conflicts
                v[jj] = Cs[(n8 + jj) * DPAD + d];
            }
            *(bf16x8*)(Xt_out + tbase + (size_t)d * N_ + n0 + n8) = v;
        }
    }
}

// ---------- K7: MFMA proj + LN ----------
__global__ void k_projln_mfma(const __bf16* __restrict__ Hn, const __bf16* __restrict__ X1n,
                              const __bf16* __restrict__ X2n, const float* __restrict__ PW,
                              const float* __restrict__ pb, const float* __restrict__ g,
                              const float* __restrict__ bb, float* __restrict__ out) {
    __shared__ __align__(16) __bf16 As[128 * DPAD];
    __shared__ __align__(16) __bf16 Bs[64 * DPAD];
    int tid = threadIdx.x;
    size_t r0 = (size_t)blockIdx.x * 128;
    int w = tid >> 6, lane = tid & 63, q = lane >> 4, lr = lane & 15;
    int mw = w * 32;
    f32x4 acc[2][4];
#pragma unroll
    for (int i = 0; i < 2; ++i)
#pragma unroll
        for (int j = 0; j < 4; ++j) acc[i][j] = (f32x4)(0.0f);
    const __bf16* srcs[3] = {Hn, X1n, X2n};
    int arow = tid >> 3, acol = (tid & 7) * 8;
    int prow = tid >> 2, pc16 = (tid & 3) * 16;
    for (int c = 0; c < 3; ++c) {
        if (c) __syncthreads();
        const __bf16* S = srcs[c] + r0 * 64;
#pragma unroll
        for (int i = 0; i < 4; ++i) {
            int r = arow + i * 32;
            *(bf16x8*)&As[r * DPAD + acol] = *(const bf16x8*)(S + (size_t)r * 64 + acol);
        }
        const float* P = PW + (size_t)prow * 192 + c * 64 + pc16;
        float4 f0 = *(const float4*)(P + 0);
        float4 f1 = *(const float4*)(P + 4);
        float4 f2 = *(const float4*)(P + 8);
        float4 f3 = *(const float4*)(P + 12);
        bf16x8 w0, w1;
        w0[0] = (__bf16)f0.x; w0[1] = (__bf16)f0.y; w0[2] = (__bf16)f0.z; w0[3] = (__bf16)f0.w;
        w0[4] = (__bf16)f1.x; w0[5] = (__bf16)f1.y; w0[6] = (__bf16)f1.z; w0[7] = (__bf16)f1.w;
        w1[0] = (__bf16)f2.x; w1[1] = (__bf16)f2.y; w1[2] = (__bf16)f2.z; w1[3] = (__bf16)f2.w;
        w1[4] = (__bf16)f3.x; w1[5] = (__bf16)f3.y; w1[6] = (__bf16)f3.z; w1[7] = (__bf16)f3.w;
        *(bf16x8*)&Bs[prow * DPAD + pc16] = w0;
        *(bf16x8*)&Bs[prow * DPAD + pc16 + 8] = w1;
        __syncthreads();
#pragma unroll
        for (int ks = 0; ks < 2; ++ks) {
            int kb = ks * 32 + q * 8;
            bf16x8 a0 = *(const bf16x8*)&As[(mw + lr) * DPAD + kb];
            bf16x8 a1 = *(const bf16x8*)&As[(mw + 16 + lr) * DPAD + kb];
#pragma unroll
            for (int tj = 0; tj < 4; ++tj) {
                bf16x8 bf = *(const bf16x8*)&Bs[(tj * 16 + lr) * DPAD + kb];
                acc[0][tj] = __builtin_amdgcn_mfma_f32_16x16x32_bf16(a0, bf, acc[0][tj], 0, 0, 0);
                acc[1][tj] = __builtin_amdgcn_mfma_f32_16x16x32_bf16(a1, bf, acc[1][tj], 0, 0, 0);
            }
        }
    }
    float pbv[4], gv[4], bv2[4];
#pragma unroll
    for (int tj = 0; tj < 4; ++tj) {
        int col = tj * 16 + lr;
        pbv[tj] = pb[col]; gv[tj] = g[col]; bv2[tj] = bb[col];
    }
#pragma unroll
    for (int ti = 0; ti < 2; ++ti) {
#pragma unroll
        for (int r = 0; r < 4; ++r) {
            float v[4];
            float s = 0.f;
#pragma unroll
            for (int tj = 0; tj < 4; ++tj) { v[tj] = acc[ti][tj][r] + pbv[tj]; s += v[tj]; }
            s += __shfl_xor(s, 1, 64); s += __shfl_xor(s, 2, 64);
            s += __shfl_xor(s, 4, 64); s += __shfl_xor(s, 8, 64);
            float mu = s * (1.0f / 64.0f);
            float qv = 0.f;
#pragma unroll
            for (int tj = 0; tj < 4; ++tj) { float d = v[tj] - mu; qv += d * d; }
            qv += __shfl_xor(qv, 1, 64); qv += __shfl_xor(qv, 2, 64);
            qv += __shfl_xor(qv, 4, 64); qv += __shfl_xor(qv, 8, 64);
            float rstd = rsqrtf(qv * (1.0f / 64.0f) + 1e-5f);
            size_t row = r0 + mw + ti * 16 + q * 4 + r;
#pragma unroll
            for (int tj = 0; tj < 4; ++tj)
                out[row * 64 + tj * 16 + lr] = (v[tj] - mu) * rstd * gv[tj] + bv2[tj];
        }
    }
}

// ---------- launch ----------
extern "C" void kernel_launch(void* const* d_in, const int* in_sizes, int n_in,
                              void* d_out, int out_size, void* d_ws, size_t ws_size,
                              hipStream_t stream) {
    const float* H    = (const float*)d_in[0];
    const float* Ast  = (const float*)d_in[1];
    const float* WQ   = (const float*)d_in[2];
    const float* WK   = (const float*)d_in[3];
    const float* WV   = (const float*)d_in[4];
    const float* PHI  = (const float*)d_in[5];
    const float* outW = (const float*)d_in[6];
    const float* outb = (const float*)d_in[7];
    const float* smag = (const float*)d_in[8];
    const float* smab = (const float*)d_in[9];
    const float* beta = (const float*)d_in[10];
    const float* PW   = (const float*)d_in[11];
    const float* pb   = (const float*)d_in[12];
    const float* aggg = (const float*)d_in[13];
    const float* aggb = (const float*)d_in[14];

    float* out  = (float*)d_out;
    float* Hsp  = out;
    float* Adyn = out + (size_t)ROWS_ * 64;
    float* Afu  = Adyn + (size_t)B_ * N_ * N_;

    float* ws   = (float*)d_ws;
    float* BUF0 = ws;                                  // fp32 phiQ -> Hp (dead after outln)
    float* phiK = ws + (size_t)ROWS_ * 64;
    float* Vm   = phiK + M_ * E_;
    float* KtV  = Vm + M_ * D_;
    float* dinv = KtV + E_ * D_;
    __bf16* mvb = (__bf16*)(dinv + N_);                // mv bf16 [B,N,64]
    __bf16* Hn  = mvb + (size_t)B_ * N_ * 64;          // H' natural bf16
    __bf16* Ht  = Hn + (size_t)ROWS_ * 64;             // H' transposed bf16 (dead after hop1)
    __bf16* Afb = Ht + (size_t)ROWS_ * 64;             // A_fused bf16
    __bf16* X1n = (__bf16*)BUF0;                       // alias dead BUF0 region
    __bf16* X1t = X1n + (size_t)ROWS_ * 64;
    __bf16* X2n = Ht;                                  // alias dead Ht region

    k_precompute<<<1, 256, 0, stream>>>(PHI, WK, WV, phiK, Vm, KtV);
    k_dinv<<<N_, 256, 0, stream>>>(Ast, dinv);
    k_phiq<<<ROWS_ / 64, 256, 0, stream>>>(H, WQ, BUF0);
    k_attn_mem<<<B_ * N_ / 4, 256, 0, stream>>>(BUF0, phiK, Vm, mvb);
    k_matt<<<ROWS_ / 64, 256, 0, stream>>>(BUF0, KtV, H);
    k_outln<<<ROWS_ / 64, 256, 0, stream>>>(BUF0, outW, outb, smag, smab, Hn, Ht);
    k_adyn_mfma<<<B_ * N_ / 16, 256, 0, stream>>>(mvb, Ast, dinv, beta, Adyn, Afu, Afb);
    k_diffuse_mfma<<<dim3(8, BT_), 256, 0, stream>>>(Afb, Ht, X1n, X1t);
    k_diffuse_mfma<<<dim3(8, BT_), 256, 0, stream>>>(Afb, X1t, X2n, (__bf16*)nullptr);
    k_projln_mfma<<<ROWS_ / 128, 256, 0, stream>>>(Hn, X1n, X2n, PW, pb, aggg, aggb, Hsp);
}